// Round 3
// baseline (107.380 us; speedup 1.0000x reference)
//
#include <hip/hip_runtime.h>
#include <hip/hip_bf16.h>
#include <climits>
#include <cfloat>

// Sampler: B=256 rows, V=128000 vocab, fp32.
// Two-kernel split:
//   A (scan): 8 segment-blocks per row, 256 thr each -> 32 waves/CU.
//     temp==0  : partial argmax (noise not read)
//     topk>0   : candidates (logit > BOUND) -> global per-row list;
//                noise exact-zeros -> global per-row list
//     topk==0  : partial gumbel argmax
//   B (finalize): per row, combine partials / rank-select k-th / threshold /
//     zero-NaN rule / gumbel over allowed candidates. Exact full-row slow
//     path on any cap overflow.
// Gumbel identity: argmax(probs/noise) == argmax(scaled - log(noise)) over
// the allowed set. noise==0 at masked position -> 0/0=NaN in ref -> first
// such index wins (np argmax NaN rule); at allowed position -> +inf
// (falls out of log(0) = -inf).

#define V_SIZE 128000
#define NV4 (V_SIZE / 4)
#define SEG 8
#define QSEG (NV4 / SEG)      // 4000 quads per segment
#define ABLOCK 256
#define BBLOCK 256
#define MONO_BLOCK 1024
#define CAP 1024              // per-row global candidate cap (expected ~795)
#define LCAP 512              // per-segment LDS staging cap (expected ~99)
#define ZCAP 64               // per-row zero-noise cap (expected ~0-4 total)
#define BOUND 10.0f

__device__ __forceinline__ unsigned fkey(float f) {
    unsigned b = __float_as_uint(f);
    return (b & 0x80000000u) ? ~b : (b | 0x80000000u);
}
__device__ __forceinline__ float fkey_inv(unsigned k) {
    unsigned b = (k & 0x80000000u) ? (k & 0x7fffffffu) : ~k;
    return __uint_as_float(b);
}

__device__ __forceinline__ void amax_upd(float& v, int& i, float nv, int ni) {
    if (nv > v || (nv == v && ni < i)) { v = nv; i = ni; }
}

template <int NT>
__device__ __forceinline__ void block_argmax_t(float& v, int& i, float* s_rv, int* s_ri) {
    constexpr int NW = NT / 64;
    const int tid = threadIdx.x, lane = tid & 63, wv = tid >> 6;
    __syncthreads();
#pragma unroll
    for (int off = 32; off > 0; off >>= 1) {
        float ov = __shfl_xor(v, off);
        int oi = __shfl_xor(i, off);
        amax_upd(v, i, ov, oi);
    }
    if (lane == 0) { s_rv[wv] = v; s_ri[wv] = i; }
    __syncthreads();
    if (tid < 64) {
        float vv = (lane < NW) ? s_rv[lane] : -INFINITY;
        int ii = (lane < NW) ? s_ri[lane] : INT_MAX;
#pragma unroll
        for (int off = 32; off > 0; off >>= 1) {
            float ov = __shfl_xor(vv, off);
            int oi = __shfl_xor(ii, off);
            amax_upd(vv, ii, ov, oi);
        }
        if (lane == 0) { s_rv[0] = vv; s_ri[0] = ii; }
    }
    __syncthreads();
    v = s_rv[0]; i = s_ri[0];
}

// argmax over one float4; strict > keeps earliest index (ascending scan order)
__device__ __forceinline__ void amax4(float4 v, int q, float& bmax, int& bidx) {
    const float m = fmaxf(fmaxf(v.x, v.y), fmaxf(v.z, v.w));
    if (m > bmax) {
        const int i0 = q << 2;
        bmax = m;
        bidx = (v.x == m) ? i0 : (v.y == m) ? i0 + 1 : (v.z == m) ? i0 + 2 : i0 + 3;
    }
}

// ============================ Kernel A: scan =============================
extern "C" __global__ void __launch_bounds__(ABLOCK)
scan_kernel(const float* __restrict__ logits, const float* __restrict__ temps,
            const int* __restrict__ topks, const float* __restrict__ noise,
            int* __restrict__ ccount, int* __restrict__ zcount,
            int* __restrict__ zidx, float* __restrict__ pval,
            int* __restrict__ pidx, float* __restrict__ cval,
            int* __restrict__ cidx) {
    const int bid = blockIdx.x;
    const int row = bid >> 3, seg = bid & 7;
    const int tid = threadIdx.x;
    const float temp = temps[row];
    const int topk = topks[row];
    const float* __restrict__ lg = logits + (size_t)row * V_SIZE;
    const float4* __restrict__ lg4 = reinterpret_cast<const float4*>(lg);
    const int q0 = seg * QSEG, q1 = q0 + QSEG;

    __shared__ float s_rv[ABLOCK / 64];
    __shared__ int s_ri[ABLOCK / 64];

    if (temp == 0.0f) {
        // ---- partial greedy argmax (noise never read) ----
        float bmax = -INFINITY; int bidx = INT_MAX;
        int q = q0 + tid;
        for (; q + 3 * ABLOCK < q1; q += 4 * ABLOCK) {
            float4 a0 = lg4[q];
            float4 a1 = lg4[q + ABLOCK];
            float4 a2 = lg4[q + 2 * ABLOCK];
            float4 a3 = lg4[q + 3 * ABLOCK];
            amax4(a0, q, bmax, bidx);
            amax4(a1, q + ABLOCK, bmax, bidx);
            amax4(a2, q + 2 * ABLOCK, bmax, bidx);
            amax4(a3, q + 3 * ABLOCK, bmax, bidx);
        }
        for (; q < q1; q += ABLOCK) amax4(lg4[q], q, bmax, bidx);
        block_argmax_t<ABLOCK>(bmax, bidx, s_rv, s_ri);
        if (tid == 0) { pval[row * SEG + seg] = bmax; pidx[row * SEG + seg] = bidx; }
        return;
    }

    if (topk > 0) {
        // ---- candidates > BOUND staged in LDS, bulk-appended to global ----
        __shared__ float s_v[LCAP];
        __shared__ int s_i[LCAP];
        __shared__ int s_n, s_base;
        if (tid == 0) s_n = 0;
        __syncthreads();
        int q = q0 + tid;
        for (; q + 3 * ABLOCK < q1; q += 4 * ABLOCK) {
            float4 a0 = lg4[q];
            float4 a1 = lg4[q + ABLOCK];
            float4 a2 = lg4[q + 2 * ABLOCK];
            float4 a3 = lg4[q + 3 * ABLOCK];
#pragma unroll
            for (int u = 0; u < 4; ++u) {
                float4 v = (u == 0) ? a0 : (u == 1) ? a1 : (u == 2) ? a2 : a3;
                const int qq = q + u * ABLOCK;
                const float m = fmaxf(fmaxf(v.x, v.y), fmaxf(v.z, v.w));
                if (m > BOUND) {  // rare ~0.6%
                    const float l[4] = {v.x, v.y, v.z, v.w};
#pragma unroll
                    for (int c = 0; c < 4; ++c) {
                        if (l[c] > BOUND) {
                            int p = atomicAdd(&s_n, 1);
                            if (p < LCAP) { s_v[p] = l[c]; s_i[p] = (qq << 2) + c; }
                        }
                    }
                }
            }
        }
        for (; q < q1; q += ABLOCK) {
            float4 v = lg4[q];
            const float m = fmaxf(fmaxf(v.x, v.y), fmaxf(v.z, v.w));
            if (m > BOUND) {
                const float l[4] = {v.x, v.y, v.z, v.w};
#pragma unroll
                for (int c = 0; c < 4; ++c) {
                    if (l[c] > BOUND) {
                        int p = atomicAdd(&s_n, 1);
                        if (p < LCAP) { s_v[p] = l[c]; s_i[p] = (q << 2) + c; }
                    }
                }
            }
        }
        // ---- noise exact-zero scan ----
        const float4* __restrict__ nz4 =
            reinterpret_cast<const float4*>(noise + (size_t)row * V_SIZE);
        q = q0 + tid;
        for (; q + 3 * ABLOCK < q1; q += 4 * ABLOCK) {
            float4 a0 = nz4[q];
            float4 a1 = nz4[q + ABLOCK];
            float4 a2 = nz4[q + 2 * ABLOCK];
            float4 a3 = nz4[q + 3 * ABLOCK];
#pragma unroll
            for (int u = 0; u < 4; ++u) {
                float4 v = (u == 0) ? a0 : (u == 1) ? a1 : (u == 2) ? a2 : a3;
                const int qq = q + u * ABLOCK;
                const float mn = fminf(fminf(v.x, v.y), fminf(v.z, v.w));
                if (mn == 0.0f) {  // Exp(1) >= 0, so min==0 iff zero present (ultra rare)
                    const float l[4] = {v.x, v.y, v.z, v.w};
#pragma unroll
                    for (int c = 0; c < 4; ++c) {
                        if (l[c] == 0.0f) {
                            int p = atomicAdd(&zcount[row], 1);
                            if (p < ZCAP) zidx[row * ZCAP + p] = (qq << 2) + c;
                        }
                    }
                }
            }
        }
        for (; q < q1; q += ABLOCK) {
            float4 v = nz4[q];
            const float mn = fminf(fminf(v.x, v.y), fminf(v.z, v.w));
            if (mn == 0.0f) {
                const float l[4] = {v.x, v.y, v.z, v.w};
#pragma unroll
                for (int c = 0; c < 4; ++c) {
                    if (l[c] == 0.0f) {
                        int p = atomicAdd(&zcount[row], 1);
                        if (p < ZCAP) zidx[row * ZCAP + p] = (q << 2) + c;
                    }
                }
            }
        }
        __syncthreads();
        const int nl = s_n;
        if (tid == 0) {
            // local staging overflow -> inflate count so B takes the exact slow path
            const int add = (nl > LCAP) ? (nl + CAP + 1) : nl;
            s_base = atomicAdd(&ccount[row], add);
        }
        __syncthreads();
        const int base = s_base;
        const int lim = min(nl, LCAP);
        for (int t = tid; t < lim; t += ABLOCK) {
            const int p = base + t;
            if (p < CAP) { cval[row * CAP + p] = s_v[t]; cidx[row * CAP + p] = s_i[t]; }
        }
        return;
    }

    // ---- topk == 0, temp > 0: partial unmasked gumbel ----
    const float4* __restrict__ nz4 =
        reinterpret_cast<const float4*>(noise + (size_t)row * V_SIZE);
    float gb = -INFINITY; int gi = INT_MAX;
    for (int q = q0 + tid; q < q1; q += ABLOCK) {
        float4 lv = lg4[q];
        float4 nv = nz4[q];
        const float l[4] = {lv.x, lv.y, lv.z, lv.w};
        const float nn[4] = {nv.x, nv.y, nv.z, nv.w};
        const int i0 = q << 2;
#pragma unroll
        for (int c = 0; c < 4; ++c) {
            const float sc = l[c] / temp;
            const float g = sc - logf(nn[c]);  // noise==0 -> +inf (matches ref)
            amax_upd(gb, gi, g, i0 + c);
        }
    }
    block_argmax_t<ABLOCK>(gb, gi, s_rv, s_ri);
    if (tid == 0) { pval[row * SEG + seg] = gb; pidx[row * SEG + seg] = gi; }
}

// ========================== Kernel B: finalize ===========================
extern "C" __global__ void __launch_bounds__(BBLOCK)
finalize_kernel(const float* __restrict__ logits, const float* __restrict__ temps,
                const int* __restrict__ topks, const float* __restrict__ noise,
                int* __restrict__ out, const int* __restrict__ ccount,
                const int* __restrict__ zcount, const int* __restrict__ zidx,
                const float* __restrict__ pval, const int* __restrict__ pidx,
                const float* __restrict__ cval, const int* __restrict__ cidx) {
    const int row = blockIdx.x;
    const int tid = threadIdx.x;
    const float temp = temps[row];
    const int topk = topks[row];

    if (temp == 0.0f || topk <= 0) {
        // combine SEG partials (greedy or full-gumbel)
        if (tid == 0) {
            float v = -INFINITY; int i = INT_MAX;
            for (int s = 0; s < SEG; ++s)
                amax_upd(v, i, pval[row * SEG + s], pidx[row * SEG + s]);
            out[row] = i;
        }
        return;
    }

    const float* __restrict__ lg = logits + (size_t)row * V_SIZE;
    const float* __restrict__ nz = noise + (size_t)row * V_SIZE;

    __shared__ float s_cv[CAP];
    __shared__ int s_ci[CAP];
    __shared__ float s_rv[BBLOCK / 64];
    __shared__ int s_ri[BBLOCK / 64];
    __shared__ float s_kth;
    __shared__ int s_nan, s_cnt;

    const int k = min(max(topk, 1), V_SIZE);
    const int n = ccount[row];
    const int zn = zcount[row];
    bool fast = (n <= CAP) && (n >= k) && (zn <= ZCAP);
    float kthv = -INFINITY;

    if (tid == 0) { s_kth = -INFINITY; s_nan = INT_MAX; }

    if (fast) {
        for (int t = tid; t < n; t += BBLOCK) {
            s_cv[t] = cval[row * CAP + t];
            s_ci[t] = cidx[row * CAP + t];
        }
        __syncthreads();
        // rank-select: k-th largest among candidates (LDS broadcast inner loop)
        for (int t = tid; t < n; t += BBLOCK) {
            const float v = s_cv[t];
            int g = 0, e = 0;
            for (int j = 0; j < n; ++j) {
                const float w = s_cv[j];
                g += (w > v) ? 1 : 0;
                e += (w == v) ? 1 : 0;
            }
            if (g < k && g + e >= k) s_kth = v;  // unique value; benign multi-write
        }
        __syncthreads();
        kthv = s_kth;
        if (!(kthv > BOUND + 0.5f)) fast = false;  // allowed set must be subset of candidates
    } else {
        __syncthreads();  // match barrier structure (uniform branch, but keep simple)
    }

    if (!fast) {
        // exact bitwise radix-select of k-th largest over the full row (rare)
        const float4* __restrict__ lg4 = reinterpret_cast<const float4*>(lg);
        unsigned prefix = 0u;
        for (int bit = 31; bit >= 0; --bit) {
            const unsigned T = prefix | (1u << bit);
            if (tid == 0) s_cnt = 0;
            __syncthreads();
            int local = 0;
            for (int q = tid; q < NV4; q += BBLOCK) {
                float4 lv = lg4[q];
                local += (fkey(lv.x) >= T);
                local += (fkey(lv.y) >= T);
                local += (fkey(lv.z) >= T);
                local += (fkey(lv.w) >= T);
            }
#pragma unroll
            for (int off = 32; off > 0; off >>= 1) local += __shfl_xor(local, off);
            if ((tid & 63) == 0) atomicAdd(&s_cnt, local);
            __syncthreads();
            const int cnt = s_cnt;
            __syncthreads();
            if (cnt >= k) prefix = T;
        }
        kthv = fkey_inv(prefix);
    }
    const float thr = kthv / temp;  // IEEE div: bit-identical to ref threshold
    __syncthreads();

    int result;
    if (fast) {
        // masked positions with zero noise -> NaN in ref -> first index wins
        for (int t = tid; t < zn; t += BBLOCK) {
            const int z = zidx[row * ZCAP + t];
            const float sc = lg[z] / temp;
            if (sc < thr) atomicMin(&s_nan, z);
        }
        // gumbel argmax over allowed candidates (scattered noise reads)
        float gb = -INFINITY; int gi = INT_MAX;
        for (int t = tid; t < n; t += BBLOCK) {
            const float sc = s_cv[t] / temp;
            if (sc >= thr) {
                const int ix = s_ci[t];
                const float g = sc - logf(nz[ix]);  // log(0) = -inf -> +inf
                amax_upd(gb, gi, g, ix);
            }
        }
        block_argmax_t<BBLOCK>(gb, gi, s_rv, s_ri);
        result = (s_nan != INT_MAX) ? s_nan : gi;
    } else {
        // full-row gumbel with inline zero handling (rare exact path)
        const float4* __restrict__ lg4 = reinterpret_cast<const float4*>(lg);
        const float4* __restrict__ nz4 = reinterpret_cast<const float4*>(nz);
        float gb = -INFINITY; int gi = INT_MAX;
        for (int q = tid; q < NV4; q += BBLOCK) {
            float4 lv = lg4[q];
            float4 nv = nz4[q];
            const float l[4] = {lv.x, lv.y, lv.z, lv.w};
            const float nn[4] = {nv.x, nv.y, nv.z, nv.w};
            const int i0 = q << 2;
#pragma unroll
            for (int c = 0; c < 4; ++c) {
                const float sc = l[c] / temp;
                if (nn[c] == 0.0f && sc < thr) atomicMin(&s_nan, i0 + c);
                if (sc >= thr) {
                    const float g = sc - logf(nn[c]);
                    amax_upd(gb, gi, g, i0 + c);
                }
            }
        }
        block_argmax_t<BBLOCK>(gb, gi, s_rv, s_ri);
        result = (s_nan != INT_MAX) ? s_nan : gi;
    }
    if (tid == 0) out[row] = result;
}

// ================= Monolithic fallback (ws too small) ====================
extern "C" __global__ void __launch_bounds__(MONO_BLOCK)
sampler_mono(const float* __restrict__ logits, const float* __restrict__ temps,
             const int* __restrict__ topks, const float* __restrict__ noise,
             int* __restrict__ out) {
    const int row = blockIdx.x;
    const int tid = threadIdx.x;
    const float temp = temps[row];
    const int topk = topks[row];
    const float* __restrict__ lg = logits + (size_t)row * V_SIZE;
    const float* __restrict__ nz = noise + (size_t)row * V_SIZE;
    const float4* __restrict__ lg4 = reinterpret_cast<const float4*>(lg);
    const float4* __restrict__ nz4 = reinterpret_cast<const float4*>(nz);

    __shared__ float s_cval[CAP];
    __shared__ int s_cidx[CAP];
    __shared__ int s_zidx[ZCAP];
    __shared__ int s_ccount, s_zcount, s_nan, s_cnt;
    __shared__ float s_rv[MONO_BLOCK / 64];
    __shared__ int s_ri[MONO_BLOCK / 64];
    __shared__ float s_kth;

    if (temp == 0.0f) {
        float bmax = -INFINITY; int bidx = INT_MAX;
        for (int q = tid; q < NV4; q += MONO_BLOCK) amax4(lg4[q], q, bmax, bidx);
        block_argmax_t<MONO_BLOCK>(bmax, bidx, s_rv, s_ri);
        if (tid == 0) out[row] = bidx;
        return;
    }

    if (tid == 0) { s_ccount = 0; s_zcount = 0; s_nan = INT_MAX; s_kth = -INFINITY; }
    __syncthreads();

    int result;
    if (topk > 0) {
        for (int q = tid; q < NV4; q += MONO_BLOCK) {
            float4 v = lg4[q];
            const float m = fmaxf(fmaxf(v.x, v.y), fmaxf(v.z, v.w));
            if (m > BOUND) {
                const float l[4] = {v.x, v.y, v.z, v.w};
#pragma unroll
                for (int c = 0; c < 4; ++c)
                    if (l[c] > BOUND) {
                        int p = atomicAdd(&s_ccount, 1);
                        if (p < CAP) { s_cval[p] = l[c]; s_cidx[p] = (q << 2) + c; }
                    }
            }
        }
        for (int q = tid; q < NV4; q += MONO_BLOCK) {
            float4 v = nz4[q];
            const float mn = fminf(fminf(v.x, v.y), fminf(v.z, v.w));
            if (mn == 0.0f) {
                const float l[4] = {v.x, v.y, v.z, v.w};
#pragma unroll
                for (int c = 0; c < 4; ++c)
                    if (l[c] == 0.0f) {
                        int p = atomicAdd(&s_zcount, 1);
                        if (p < ZCAP) s_zidx[p] = (q << 2) + c;
                    }
            }
        }
        __syncthreads();
        const int k = min(max(topk, 1), V_SIZE);
        const int n = s_ccount;
        float kthv = -INFINITY;
        bool cands_ok = (n <= CAP) && (n >= k) && (s_zcount <= ZCAP);
        if (cands_ok) {
            for (int t = tid; t < n; t += MONO_BLOCK) {
                const float v = s_cval[t];
                int g = 0, e = 0;
                for (int j = 0; j < n; ++j) {
                    const float w = s_cval[j];
                    g += (w > v) ? 1 : 0;
                    e += (w == v) ? 1 : 0;
                }
                if (g < k && g + e >= k) s_kth = v;
            }
            __syncthreads();
            kthv = s_kth;
            if (!(kthv > BOUND + 0.5f)) cands_ok = false;
        }
        if (!cands_ok) {
            unsigned prefix = 0u;
            for (int bit = 31; bit >= 0; --bit) {
                const unsigned T = prefix | (1u << bit);
                if (tid == 0) s_cnt = 0;
                __syncthreads();
                int local = 0;
                for (int q = tid; q < NV4; q += MONO_BLOCK) {
                    float4 lv = lg4[q];
                    local += (fkey(lv.x) >= T);
                    local += (fkey(lv.y) >= T);
                    local += (fkey(lv.z) >= T);
                    local += (fkey(lv.w) >= T);
                }
#pragma unroll
                for (int off = 32; off > 0; off >>= 1) local += __shfl_xor(local, off);
                if ((tid & 63) == 0) atomicAdd(&s_cnt, local);
                __syncthreads();
                const int cnt = s_cnt;
                __syncthreads();
                if (cnt >= k) prefix = T;
            }
            kthv = fkey_inv(prefix);
        }
        const float thr = kthv / temp;
        float gb = -INFINITY; int gi = INT_MAX;
        if (cands_ok) {
            const int zn = min(s_zcount, ZCAP);
            for (int t = tid; t < zn; t += MONO_BLOCK) {
                const int z = s_zidx[t];
                if (lg[z] / temp < thr) atomicMin(&s_nan, z);
            }
            for (int t = tid; t < n; t += MONO_BLOCK) {
                const float sc = s_cval[t] / temp;
                if (sc >= thr) {
                    const int ix = s_cidx[t];
                    amax_upd(gb, gi, sc - logf(nz[ix]), ix);
                }
            }
        } else {
            for (int q = tid; q < NV4; q += MONO_BLOCK) {
                float4 lv = lg4[q];
                float4 nv = nz4[q];
                const float l[4] = {lv.x, lv.y, lv.z, lv.w};
                const float nn[4] = {nv.x, nv.y, nv.z, nv.w};
                const int i0 = q << 2;
#pragma unroll
                for (int c = 0; c < 4; ++c) {
                    const float sc = l[c] / temp;
                    if (nn[c] == 0.0f && sc < thr) atomicMin(&s_nan, i0 + c);
                    if (sc >= thr) amax_upd(gb, gi, sc - logf(nn[c]), i0 + c);
                }
            }
        }
        block_argmax_t<MONO_BLOCK>(gb, gi, s_rv, s_ri);
        result = (s_nan != INT_MAX) ? s_nan : gi;
    } else {
        float gb = -INFINITY; int gi = INT_MAX;
        for (int q = tid; q < NV4; q += MONO_BLOCK) {
            float4 lv = lg4[q];
            float4 nv = nz4[q];
            const float l[4] = {lv.x, lv.y, lv.z, lv.w};
            const float nn[4] = {nv.x, nv.y, nv.z, nv.w};
            const int i0 = q << 2;
#pragma unroll
            for (int c = 0; c < 4; ++c) {
                const float sc = l[c] / temp;
                amax_upd(gb, gi, sc - logf(nn[c]), i0 + c);
            }
        }
        block_argmax_t<MONO_BLOCK>(gb, gi, s_rv, s_ri);
        result = gi;
    }
    if (tid == 0) out[row] = result;
}

// ================================ host ===================================
extern "C" void kernel_launch(void* const* d_in, const int* in_sizes, int n_in,
                              void* d_out, int out_size, void* d_ws, size_t ws_size,
                              hipStream_t stream) {
    const float* logits = (const float*)d_in[0];
    const float* temps  = (const float*)d_in[1];
    const int*   topks  = (const int*)d_in[2];
    const float* noise  = (const float*)d_in[3];
    int* out = (int*)d_out;
    const int B = in_sizes[1];  // 256 rows

    // workspace layout
    size_t off = 0;
    char* base = (char*)d_ws;
    int*   ccount = (int*)(base + off);   off += (size_t)B * 4;
    int*   zcount = (int*)(base + off);   off += (size_t)B * 4;
    int*   zidx   = (int*)(base + off);   off += (size_t)B * ZCAP * 4;
    float* pval   = (float*)(base + off); off += (size_t)B * SEG * 4;
    int*   pidx   = (int*)(base + off);   off += (size_t)B * SEG * 4;
    float* cval   = (float*)(base + off); off += (size_t)B * CAP * 4;
    int*   cidx   = (int*)(base + off);   off += (size_t)B * CAP * 4;

    if (ws_size < off) {
        sampler_mono<<<B, MONO_BLOCK, 0, stream>>>(logits, temps, topks, noise, out);
        return;
    }

    hipMemsetAsync(d_ws, 0, (size_t)B * 8, stream);  // ccount + zcount
    scan_kernel<<<B * SEG, ABLOCK, 0, stream>>>(logits, temps, topks, noise,
                                                ccount, zcount, zidx, pval, pidx,
                                                cval, cidx);
    finalize_kernel<<<B, BBLOCK, 0, stream>>>(logits, temps, topks, noise, out,
                                              ccount, zcount, zidx, pval, pidx,
                                              cval, cidx);
}

// Round 6
// 72.022 us; speedup vs baseline: 1.4909x; 1.4909x over previous
//
#include <hip/hip_runtime.h>
#include <climits>
#include <cfloat>

// Sampler: B=256 rows, V=128000 vocab, fp32. Monolithic (R2 shell, passed):
// one block per row, 1024 threads.
//   temp==0          -> greedy argmax over logits (noise not read)
//   temp>0 && topk>0 -> candidate scan (logit > BOUND) + noise-zero scan,
//                       exact k-th threshold, gumbel argmax over allowed set
//   temp>0 && topk==0-> full-row gumbel argmax
// This round: 8-deep load batching + grouped rarity tests in the two
// streaming scans (ILP probe). No u64 atomics, no grid-stride (R4/R5 crashed).
//
// Gumbel identity: argmax(probs/noise) == argmax(scaled - log(noise)) over
// the allowed set. noise==0 at masked position -> 0/0=NaN in ref -> first
// such index wins (np argmax NaN rule); at allowed position -> +inf
// (falls out of log(0) = -inf).

#define V_SIZE 128000
#define NV4 (V_SIZE / 4)
#define BLOCK 1024
#define NWAVES (BLOCK / 64)
#define CAP 4096
#define ZCAP 64
#define BOUND 10.0f

__device__ __forceinline__ unsigned fkey(float f) {
    unsigned b = __float_as_uint(f);
    return (b & 0x80000000u) ? ~b : (b | 0x80000000u);
}
__device__ __forceinline__ float fkey_inv(unsigned k) {
    unsigned b = (k & 0x80000000u) ? (k & 0x7fffffffu) : ~k;
    return __uint_as_float(b);
}

__device__ __forceinline__ void amax_upd(float& v, int& i, float nv, int ni) {
    if (nv > v || (nv == v && ni < i)) { v = nv; i = ni; }
}

__device__ __forceinline__ float max4(float4 v) {
    return fmaxf(fmaxf(v.x, v.y), fmaxf(v.z, v.w));
}
__device__ __forceinline__ float min4(float4 v) {
    return fminf(fminf(v.x, v.y), fminf(v.z, v.w));
}

__device__ __forceinline__ void block_argmax(float& v, int& i, float* s_rv, int* s_ri) {
    const int tid = threadIdx.x, lane = tid & 63, wv = tid >> 6;
    __syncthreads();  // protect s_rv/s_ri reuse across calls
#pragma unroll
    for (int off = 32; off > 0; off >>= 1) {
        float ov = __shfl_xor(v, off);
        int oi = __shfl_xor(i, off);
        amax_upd(v, i, ov, oi);
    }
    if (lane == 0) { s_rv[wv] = v; s_ri[wv] = i; }
    __syncthreads();
    if (tid < 64) {
        float vv = (lane < NWAVES) ? s_rv[lane] : -INFINITY;
        int ii = (lane < NWAVES) ? s_ri[lane] : INT_MAX;
#pragma unroll
        for (int off = 8; off > 0; off >>= 1) {
            float ov = __shfl_xor(vv, off);
            int oi = __shfl_xor(ii, off);
            amax_upd(vv, ii, ov, oi);
        }
        if (lane == 0) { s_rv[0] = vv; s_ri[0] = ii; }
    }
    __syncthreads();
    v = s_rv[0]; i = s_ri[0];
}

// argmax over one float4; earliest index on ties (ascending scan order)
__device__ __forceinline__ void amax4(float4 v, int q, float& bmax, int& bidx) {
    const float m = max4(v);
    if (m > bmax) {
        const int i0 = q << 2;
        bmax = m;
        bidx = (v.x == m) ? i0 : (v.y == m) ? i0 + 1 : (v.z == m) ? i0 + 2 : i0 + 3;
    }
}

__device__ __forceinline__ void cand4(float4 v, int q, float* s_cval, int* s_cidx,
                                      int* s_ccount) {
    if (max4(v) > BOUND) {
        const int i0 = q << 2;
        const float l[4] = {v.x, v.y, v.z, v.w};
#pragma unroll
        for (int c = 0; c < 4; ++c) {
            if (l[c] > BOUND) {
                int p = atomicAdd(s_ccount, 1);
                if (p < CAP) { s_cval[p] = l[c]; s_cidx[p] = i0 + c; }
            }
        }
    }
}

__device__ __forceinline__ void zero4(float4 v, int q, int* s_zidx, int* s_zcount) {
    if (min4(v) == 0.0f) {  // Exp(1) >= 0: min==0 iff an exact zero (ultra rare)
        const int i0 = q << 2;
        const float l[4] = {v.x, v.y, v.z, v.w};
#pragma unroll
        for (int c = 0; c < 4; ++c) {
            if (l[c] == 0.0f) {
                int p = atomicAdd(s_zcount, 1);
                if (p < ZCAP) s_zidx[p] = i0 + c;
            }
        }
    }
}

extern "C" __global__ void __launch_bounds__(BLOCK)
sampler_kernel(const float* __restrict__ logits, const float* __restrict__ temps,
               const int* __restrict__ topks, const float* __restrict__ noise,
               int* __restrict__ out) {
    const int row = blockIdx.x;
    const int tid = threadIdx.x;
    const float temp = temps[row];
    const int topk = topks[row];
    const float* __restrict__ lg = logits + (size_t)row * V_SIZE;
    const float* __restrict__ nz = noise + (size_t)row * V_SIZE;
    const float4* __restrict__ lg4 = reinterpret_cast<const float4*>(lg);
    const float4* __restrict__ nz4 = reinterpret_cast<const float4*>(nz);

    __shared__ float s_cval[CAP];
    __shared__ int s_cidx[CAP];
    __shared__ int s_zidx[ZCAP];
    __shared__ int s_ccount, s_zcount, s_nan, s_cnt;
    __shared__ float s_rv[NWAVES];
    __shared__ int s_ri[NWAVES];
    __shared__ float s_kth;

    // ---------------- temp == 0: greedy argmax only (noise never read) -------
    if (temp == 0.0f) {
        float bmax = -INFINITY; int bidx = INT_MAX;
        int q = tid;
        for (; q + 3 * BLOCK < NV4; q += 4 * BLOCK) {
            float4 a0 = lg4[q];
            float4 a1 = lg4[q + BLOCK];
            float4 a2 = lg4[q + 2 * BLOCK];
            float4 a3 = lg4[q + 3 * BLOCK];
            amax4(a0, q, bmax, bidx);
            amax4(a1, q + BLOCK, bmax, bidx);
            amax4(a2, q + 2 * BLOCK, bmax, bidx);
            amax4(a3, q + 3 * BLOCK, bmax, bidx);
        }
        for (; q < NV4; q += BLOCK) amax4(lg4[q], q, bmax, bidx);
        block_argmax(bmax, bidx, s_rv, s_ri);
        if (tid == 0) out[row] = bidx;
        return;
    }

    if (tid == 0) { s_ccount = 0; s_zcount = 0; s_nan = INT_MAX; s_kth = -INFINITY; }
    __syncthreads();

    int result;
    if (topk > 0) {
        // ---- scan 1: logits -> candidates (8-deep, grouped rarity test) ----
        int q = tid;
        for (; q + 7 * BLOCK < NV4; q += 8 * BLOCK) {
            const float4 a0 = lg4[q];
            const float4 a1 = lg4[q + BLOCK];
            const float4 a2 = lg4[q + 2 * BLOCK];
            const float4 a3 = lg4[q + 3 * BLOCK];
            const float4 a4 = lg4[q + 4 * BLOCK];
            const float4 a5 = lg4[q + 5 * BLOCK];
            const float4 a6 = lg4[q + 6 * BLOCK];
            const float4 a7 = lg4[q + 7 * BLOCK];
            const float mA = fmaxf(fmaxf(max4(a0), max4(a1)), fmaxf(max4(a2), max4(a3)));
            const float mB = fmaxf(fmaxf(max4(a4), max4(a5)), fmaxf(max4(a6), max4(a7)));
            if (mA > BOUND) {  // rare ~2.5% of 16-quad... per-4-quad groups
                cand4(a0, q, s_cval, s_cidx, &s_ccount);
                cand4(a1, q + BLOCK, s_cval, s_cidx, &s_ccount);
                cand4(a2, q + 2 * BLOCK, s_cval, s_cidx, &s_ccount);
                cand4(a3, q + 3 * BLOCK, s_cval, s_cidx, &s_ccount);
            }
            if (mB > BOUND) {
                cand4(a4, q + 4 * BLOCK, s_cval, s_cidx, &s_ccount);
                cand4(a5, q + 5 * BLOCK, s_cval, s_cidx, &s_ccount);
                cand4(a6, q + 6 * BLOCK, s_cval, s_cidx, &s_ccount);
                cand4(a7, q + 7 * BLOCK, s_cval, s_cidx, &s_ccount);
            }
        }
        for (; q < NV4; q += BLOCK) cand4(lg4[q], q, s_cval, s_cidx, &s_ccount);

        // ---- scan 2: noise -> exact-zero positions (8-deep, grouped) ----
        q = tid;
        for (; q + 7 * BLOCK < NV4; q += 8 * BLOCK) {
            const float4 a0 = nz4[q];
            const float4 a1 = nz4[q + BLOCK];
            const float4 a2 = nz4[q + 2 * BLOCK];
            const float4 a3 = nz4[q + 3 * BLOCK];
            const float4 a4 = nz4[q + 4 * BLOCK];
            const float4 a5 = nz4[q + 5 * BLOCK];
            const float4 a6 = nz4[q + 6 * BLOCK];
            const float4 a7 = nz4[q + 7 * BLOCK];
            const float mA = fminf(fminf(min4(a0), min4(a1)), fminf(min4(a2), min4(a3)));
            const float mB = fminf(fminf(min4(a4), min4(a5)), fminf(min4(a6), min4(a7)));
            if (mA == 0.0f) {  // essentially never
                zero4(a0, q, s_zidx, &s_zcount);
                zero4(a1, q + BLOCK, s_zidx, &s_zcount);
                zero4(a2, q + 2 * BLOCK, s_zidx, &s_zcount);
                zero4(a3, q + 3 * BLOCK, s_zidx, &s_zcount);
            }
            if (mB == 0.0f) {
                zero4(a4, q + 4 * BLOCK, s_zidx, &s_zcount);
                zero4(a5, q + 5 * BLOCK, s_zidx, &s_zcount);
                zero4(a6, q + 6 * BLOCK, s_zidx, &s_zcount);
                zero4(a7, q + 7 * BLOCK, s_zidx, &s_zcount);
            }
        }
        for (; q < NV4; q += BLOCK) zero4(nz4[q], q, s_zidx, &s_zcount);
        __syncthreads();

        const int k = min(max(topk, 1), V_SIZE);
        const int n = s_ccount;
        float kthv = -INFINITY;
        bool cands_ok = (n <= CAP) && (n >= k);
        if (cands_ok) {
            // rank-select k-th largest among candidates (LDS broadcast inner loop)
            for (int t = tid; t < n; t += BLOCK) {
                float v = s_cval[t];
                int g = 0, e = 0;
                for (int j = 0; j < n; ++j) {
                    float w = s_cval[j];
                    g += (w > v) ? 1 : 0;
                    e += (w == v) ? 1 : 0;
                }
                if (g < k && g + e >= k) s_kth = v;  // unique value; benign multi-write
            }
            __syncthreads();
            kthv = s_kth;
            if (!(kthv > BOUND + 0.5f)) cands_ok = false;  // allowed ⊆ candidates required
        }
        if (!cands_ok) {
            // exact bitwise radix-select over the full row (never expected to run)
            unsigned prefix = 0u;
            for (int bit = 31; bit >= 0; --bit) {
                const unsigned T = prefix | (1u << bit);
                if (tid == 0) s_cnt = 0;
                __syncthreads();
                int local = 0;
                for (int qq = tid; qq < NV4; qq += BLOCK) {
                    float4 lv = lg4[qq];
                    local += (fkey(lv.x) >= T);
                    local += (fkey(lv.y) >= T);
                    local += (fkey(lv.z) >= T);
                    local += (fkey(lv.w) >= T);
                }
#pragma unroll
                for (int off = 32; off > 0; off >>= 1) local += __shfl_xor(local, off);
                if ((tid & 63) == 0) atomicAdd(&s_cnt, local);
                __syncthreads();
                const int cnt = s_cnt;
                __syncthreads();
                if (cnt >= k) prefix = T;
            }
            kthv = fkey_inv(prefix);
        }
        const float thr = kthv / temp;  // IEEE div: bit-identical to ref threshold

        // zero-noise positions at masked indices -> NaN in reference -> first wins
        const int zn = min(s_zcount, ZCAP);
        for (int t = tid; t < zn; t += BLOCK) {
            const int z = s_zidx[t];
            const float sc = lg[z] / temp;
            if (sc < thr) atomicMin(&s_nan, z);
        }

        // gumbel argmax over allowed set (scattered noise reads, ~k matter)
        float gb = -INFINITY; int gbi = INT_MAX;
        if (cands_ok) {
            for (int t = tid; t < n; t += BLOCK) {
                const float sc = s_cval[t] / temp;
                if (sc >= thr) {
                    const int ix = s_cidx[t];
                    const float g = sc - logf(nz[ix]);  // log(0) = -inf -> +inf
                    amax_upd(gb, gbi, g, ix);
                }
            }
        } else {
            for (int qq = tid; qq < NV4; qq += BLOCK) {
                float4 lv = lg4[qq];
                float4 nv = nz4[qq];
                const float l[4] = {lv.x, lv.y, lv.z, lv.w};
                const float nn[4] = {nv.x, nv.y, nv.z, nv.w};
                const int i0 = qq << 2;
#pragma unroll
                for (int c = 0; c < 4; ++c) {
                    const float sc = l[c] / temp;
                    if (sc >= thr) {
                        const float g = sc - logf(nn[c]);
                        amax_upd(gb, gbi, g, i0 + c);
                    }
                }
            }
        }
        block_argmax(gb, gbi, s_rv, s_ri);
        result = (s_nan != INT_MAX) ? s_nan : gbi;
    } else {
        // ---- topk == 0, temp > 0: unmasked gumbel over the full row ----
        float gb = -INFINITY; int gbi = INT_MAX;
        for (int qq = tid; qq < NV4; qq += BLOCK) {
            float4 lv = lg4[qq];
            float4 nv = nz4[qq];
            const float l[4] = {lv.x, lv.y, lv.z, lv.w};
            const float nn[4] = {nv.x, nv.y, nv.z, nv.w};
            const int i0 = qq << 2;
#pragma unroll
            for (int c = 0; c < 4; ++c) {
                const float sc = l[c] / temp;
                const float g = sc - logf(nn[c]);  // noise==0 -> +inf, matches ref inf
                amax_upd(gb, gbi, g, i0 + c);
            }
        }
        block_argmax(gb, gbi, s_rv, s_ri);
        result = gbi;
    }
    if (tid == 0) out[row] = result;
}

extern "C" void kernel_launch(void* const* d_in, const int* in_sizes, int n_in,
                              void* d_out, int out_size, void* d_ws, size_t ws_size,
                              hipStream_t stream) {
    const float* logits = (const float*)d_in[0];
    const float* temps  = (const float*)d_in[1];
    const int*   topks  = (const int*)d_in[2];
    const float* noise  = (const float*)d_in[3];
    int* out = (int*)d_out;
    const int B = in_sizes[1];  // 256 rows
    sampler_kernel<<<B, BLOCK, 0, stream>>>(logits, temps, topks, noise, out);
}